// Round 8
// baseline (267.576 us; speedup 1.0000x reference)
//
#include <hip/hip_runtime.h>
#include <cstdint>

#define NNODES 100000
#define NEDGES 1600000
#define NBKT   196          // ceil(NNODES / 512); bucket = dst >> 9
#define CAP    9216         // per-bucket capacity: mean 8192 + ~11 sigma
#define BIN_CHUNK 4096
#define GBIN ((NEDGES + BIN_CHUNK - 1) / BIN_CHUNK)   // 391
#define GCVT (NNODES * 16 / 256)                      // 6250 (1 uint4/thread)
#define GWPK 24                                       // weight-pack blocks (6144 thr)

typedef __attribute__((ext_vector_type(8))) __bf16 bf16x8;
typedef __attribute__((ext_vector_type(4))) float f32x4;
typedef short v2s __attribute__((ext_vector_type(2)));

__device__ __forceinline__ unsigned short f2bf_rne(float f) {
    unsigned int u = __float_as_uint(f);
    u += 0x7fffu + ((u >> 16) & 1u);
    return (unsigned short)(u >> 16);
}
// involutive monotone map: bf16 float order <-> signed i16 order (per packed half)
__device__ __forceinline__ unsigned encdec(unsigned u) {
    return u ^ (((u & 0x80008000u) >> 15) * 0x7FFFu);
}
__device__ __forceinline__ unsigned pkmax(unsigned a, unsigned b) {
    v2s r = __builtin_elementwise_max(__builtin_bit_cast(v2s, a), __builtin_bit_cast(v2s, b));
    return __builtin_bit_cast(unsigned, r);
}
__device__ __forceinline__ uint4 pkmax4(uint4 a, uint4 b) {
    uint4 r;
    r.x = pkmax(a.x, b.x); r.y = pkmax(a.y, b.y);
    r.z = pkmax(a.z, b.z); r.w = pkmax(a.w, b.w);
    return r;
}

// ===== 2-SLICE layout =====
// Feature matrices [N][128] bf16 stored as 2 slices of 64 channels:
//   uint4 index(slice s, node n, j) = ((size_t)s*N + n)*8 + j,  j in [0,8)

// ---------------- prep: bin edges | encode x | pack weights (one kernel) -----
__global__ __launch_bounds__(256) void prep_kernel(
        const int* __restrict__ src, const int* __restrict__ dst,
        unsigned int* __restrict__ binArr, int* __restrict__ bucketFill,
        const float4* __restrict__ xin, uint4* __restrict__ xeout,
        const float* __restrict__ W1l, const float* __restrict__ W1r,
        const float* __restrict__ W2l, const float* __restrict__ W2r,
        uint4* __restrict__ Wf1, uint4* __restrict__ Wf2, int nE) {
    if (blockIdx.x >= GBIN + GCVT) {
        // ---- weight pack (24 blocks) ----
        int t = (blockIdx.x - GBIN - GCVT) * 256 + threadIdx.x;   // 0..6143
        unsigned short s[8];
        if (t < 4096) {                           // layer 1: BN=128, NT=8
            int h = t >> 11, kt = (t >> 9) & 3, nt = (t >> 6) & 7, lane = t & 63;
            const float* W = h ? W1r : W1l;
            int k0 = kt * 32 + (lane >> 4) * 8;
            int col = nt * 16 + (lane & 15);
#pragma unroll
            for (int jj = 0; jj < 8; ++jj) s[jj] = f2bf_rne(W[(k0 + jj) * 128 + col]);
            uint4 o;
            o.x = (unsigned)s[0] | ((unsigned)s[1] << 16);
            o.y = (unsigned)s[2] | ((unsigned)s[3] << 16);
            o.z = (unsigned)s[4] | ((unsigned)s[5] << 16);
            o.w = (unsigned)s[6] | ((unsigned)s[7] << 16);
            Wf1[t] = o;
        } else {                                  // layer 2: BN=64, NT=4
            int u = t - 4096;                     // 0..2047
            int h = u >> 10, kt = (u >> 8) & 3, nt = (u >> 6) & 3, lane = u & 63;
            const float* W = h ? W2r : W2l;
            int k0 = kt * 32 + (lane >> 4) * 8;
            int col = nt * 16 + (lane & 15);
#pragma unroll
            for (int jj = 0; jj < 8; ++jj) s[jj] = f2bf_rne(W[(k0 + jj) * 64 + col]);
            uint4 o;
            o.x = (unsigned)s[0] | ((unsigned)s[1] << 16);
            o.y = (unsigned)s[2] | ((unsigned)s[3] << 16);
            o.z = (unsigned)s[4] | ((unsigned)s[5] << 16);
            o.w = (unsigned)s[6] | ((unsigned)s[7] << 16);
            Wf2[u] = o;
        }
        return;
    }
    if (blockIdx.x >= GBIN) {
        // ---- encode x into sliced layout ----
        int t = (blockIdx.x - GBIN) * 256 + threadIdx.x;  // 0..1.6M-1 sliced uint4 idx
        int s = t / (NNODES * 8);
        int rem = t - s * (NNODES * 8);
        int n = rem >> 3, j = rem & 7;
        int f = n * 32 + s * 16 + j * 2;                  // float4 idx (ch 64s+8j)
        float4 v0 = xin[f], v1 = xin[f + 1];
        uint4 o;
        o.x = encdec((unsigned)f2bf_rne(v0.x) | ((unsigned)f2bf_rne(v0.y) << 16));
        o.y = encdec((unsigned)f2bf_rne(v0.z) | ((unsigned)f2bf_rne(v0.w) << 16));
        o.z = encdec((unsigned)f2bf_rne(v1.x) | ((unsigned)f2bf_rne(v1.y) << 16));
        o.w = encdec((unsigned)f2bf_rne(v1.z) | ((unsigned)f2bf_rne(v1.w) << 16));
        xeout[t] = o;
        return;
    }
    // ---- bin: entry = (dst&511)<<17 | src ----
    __shared__ unsigned int stage[BIN_CHUNK];
    __shared__ unsigned char bof[BIN_CHUNK];
    __shared__ int cnt[256], cstart[256], cfill[256], gbase[256];
    const int tid = threadIdx.x;
    const int blockStart = blockIdx.x * BIN_CHUNK;
    const int chunkN = min(BIN_CHUNK, nE - blockStart);
    cnt[tid] = 0;
    __syncthreads();
    int myd[16], mys[16];
#pragma unroll
    for (int i = 0; i < 16; ++i) {
        int idx = i * 256 + tid;
        if (idx < chunkN) {
            myd[i] = dst[blockStart + idx];
            mys[i] = src[blockStart + idx];
            atomicAdd(&cnt[myd[i] >> 9], 1);
        }
    }
    __syncthreads();
    int v = cnt[tid];
    for (int off = 1; off < 256; off <<= 1) {
        int add = (tid >= off) ? cnt[tid - off] : 0;
        __syncthreads();
        cnt[tid] += add;
        __syncthreads();
    }
    cstart[tid] = cnt[tid] - v;
    cfill[tid] = cnt[tid] - v;
    if (tid < NBKT && v > 0) gbase[tid] = atomicAdd(&bucketFill[tid], v);
    __syncthreads();
#pragma unroll
    for (int i = 0; i < 16; ++i) {
        int idx = i * 256 + tid;
        if (idx < chunkN) {
            int b = myd[i] >> 9;
            int p = atomicAdd(&cfill[b], 1);
            stage[p] = ((unsigned)(myd[i] & 511) << 17) | (unsigned)mys[i];
            bof[p] = (unsigned char)b;
        }
    }
    __syncthreads();
#pragma unroll
    for (int i = 0; i < 16; ++i) {
        int idx = i * 256 + tid;
        if (idx < chunkN) {
            int b = bof[idx];
            int slot = gbase[b] + (idx - cstart[b]);
            if (slot < CAP) binArr[(size_t)b * CAP + slot] = stage[idx];
        }
    }
}

// ---------------- per-bucket CSR build, all in LDS ----------------
__global__ __launch_bounds__(512) void build_csr_kernel(
        const unsigned int* __restrict__ binArr, const int* __restrict__ bucketFill,
        unsigned int* __restrict__ sortedSrc,
        int* __restrict__ rowBeg, int* __restrict__ rowEnd) {
    __shared__ unsigned int stage[CAP];
    __shared__ int ncnt[512], nstart[512];
    const int b = blockIdx.x;
    const int t = threadIdx.x;
    const int cnt_b = min(bucketFill[b], CAP);
    ncnt[t] = 0;
    __syncthreads();
    for (int i = t; i < cnt_b; i += 512) {
        unsigned int e = binArr[(size_t)b * CAP + i];
        stage[i] = e;
        atomicAdd(&ncnt[e >> 17], 1);
    }
    __syncthreads();
    int v = ncnt[t];
    for (int off = 1; off < 512; off <<= 1) {
        int add = (t >= off) ? ncnt[t - off] : 0;
        __syncthreads();
        ncnt[t] += add;
        __syncthreads();
    }
    int start = ncnt[t] - v;
    nstart[t] = start;
    int n = (b << 9) + t;
    if (n < NNODES) {
        rowBeg[n] = b * CAP + start;
        rowEnd[n] = b * CAP + start + v;
    }
    __syncthreads();
    for (int i = t; i < cnt_b; i += 512) {
        unsigned int e = stage[i];
        int p = atomicAdd(&nstart[e >> 17], 1);
        sortedSrc[(size_t)b * CAP + p] = e & 0x1FFFFu;
    }
}

// ---------------- FUSED aggregate + GEMM, 2-tile software pipeline ----------
// Block = 32 nodes (2 tiles x 16), double-buffered LDS. Pipeline keeps gather
// loads in flight during the GEMM window:
//   gather t0 -> lds0 -> bar | issue gather t1 | GEMM t0 | t1 -> lds1 -> bar | GEMM t1
template<int BN, bool RELU, bool ENCOUT, typename OutT>
__global__ __launch_bounds__(256) void sage_fused2(
        const uint4* __restrict__ xsl,          // sliced encoded features
        const int* __restrict__ rowBeg,
        const int* __restrict__ rowEnd,
        const unsigned int* __restrict__ sortedSrc,
        const uint4* __restrict__ Wf,           // fragment-packed weights
        const float* __restrict__ bias,         // [BN] f32
        OutT* __restrict__ C,                   // ENCOUT: sliced bf16; else [M][BN] f32
        int nN) {
    constexpr int NT = BN / 16;                 // packed column tiles (8 or 4)
    constexpr int NTW = BN / 64;                // column tiles per wave (2 or 1)
    __shared__ uint4 ldsb[2][16][17];           // +1 pad
    const int wv   = threadIdx.x >> 6;
    const int lane = threadIdx.x & 63;
    const int n0   = blockIdx.x * 32;           // grid exact: 3125*32 == NNODES

    // gather lane mapping (per wave: 8 nodes x 1 slice)
    const int s  = wv & 1;
    const int nh = wv >> 1;
    const int k  = lane >> 3;
    const int j  = lane & 7;
    const int kb = k << 3;
    const size_t srow = (size_t)s * nN;
    const int nloc = nh * 8 + k;                // node row within a 16-tile

    // GEMM lane mapping
    const int quad = lane >> 4;
    const int mrow = lane & 15;

    // ---- prefetch both tiles' bounds + first-16 ids ----
    const int nT0 = n0 + nloc, nT1 = n0 + 16 + nloc;
    const int beg0 = rowBeg[nT0], end0 = rowEnd[nT0];
    const int beg1 = rowBeg[nT1], end1 = rowEnd[nT1];
    const int m0 = end0 - beg0, m1 = end1 - beg1;
    int p0a = 0, p0b = 0, p1a = 0, p1b = 0;
    if (m0 > 0) {
        p0a = (int)sortedSrc[min(beg0 + j,     end0 - 1)];
        p0b = (int)sortedSrc[min(beg0 + 8 + j, end0 - 1)];
    }
    if (m1 > 0) {
        p1a = (int)sortedSrc[min(beg1 + j,     end1 - 1)];
        p1b = (int)sortedSrc[min(beg1 + 8 + j, end1 - 1)];
    }

#define GATHER16(idvA, idvB, accOut)                                           \
    {                                                                          \
        int a0 = __shfl(idvA, kb | 0), a1 = __shfl(idvA, kb | 1);              \
        int a2 = __shfl(idvA, kb | 2), a3 = __shfl(idvA, kb | 3);              \
        int a4 = __shfl(idvA, kb | 4), a5 = __shfl(idvA, kb | 5);              \
        int a6 = __shfl(idvA, kb | 6), a7 = __shfl(idvA, kb | 7);              \
        int b0 = __shfl(idvB, kb | 0), b1 = __shfl(idvB, kb | 1);              \
        int b2 = __shfl(idvB, kb | 2), b3 = __shfl(idvB, kb | 3);              \
        int b4 = __shfl(idvB, kb | 4), b5 = __shfl(idvB, kb | 5);              \
        int b6 = __shfl(idvB, kb | 6), b7 = __shfl(idvB, kb | 7);              \
        uint4 q0  = xsl[(srow + a0) * 8 + j];                                  \
        uint4 q1  = xsl[(srow + a1) * 8 + j];                                  \
        uint4 q2  = xsl[(srow + a2) * 8 + j];                                  \
        uint4 q3  = xsl[(srow + a3) * 8 + j];                                  \
        uint4 q4  = xsl[(srow + a4) * 8 + j];                                  \
        uint4 q5  = xsl[(srow + a5) * 8 + j];                                  \
        uint4 q6  = xsl[(srow + a6) * 8 + j];                                  \
        uint4 q7  = xsl[(srow + a7) * 8 + j];                                  \
        uint4 q8  = xsl[(srow + b0) * 8 + j];                                  \
        uint4 q9  = xsl[(srow + b1) * 8 + j];                                  \
        uint4 q10 = xsl[(srow + b2) * 8 + j];                                  \
        uint4 q11 = xsl[(srow + b3) * 8 + j];                                  \
        uint4 q12 = xsl[(srow + b4) * 8 + j];                                  \
        uint4 q13 = xsl[(srow + b5) * 8 + j];                                  \
        uint4 q14 = xsl[(srow + b6) * 8 + j];                                  \
        uint4 q15 = xsl[(srow + b7) * 8 + j];                                  \
        accOut = pkmax4(                                                       \
            pkmax4(pkmax4(pkmax4(q0, q1), pkmax4(q2, q3)),                     \
                   pkmax4(pkmax4(q4, q5), pkmax4(q6, q7))),                    \
            pkmax4(pkmax4(pkmax4(q8, q9), pkmax4(q10, q11)),                   \
                   pkmax4(pkmax4(q12, q13), pkmax4(q14, q15))));               \
    }

#define GATHER_TAIL(beg, end, m, acc)                                          \
    {                                                                          \
        int maxm = m;                                                          \
        maxm = max(maxm, __shfl_xor(maxm, 8));                                 \
        maxm = max(maxm, __shfl_xor(maxm, 16));                                \
        maxm = max(maxm, __shfl_xor(maxm, 32));                                \
        for (int e0 = 16; e0 < maxm; e0 += 8) {                                \
            if (e0 < m) {                                                      \
                int idt = (int)sortedSrc[min(beg + e0 + j, end - 1)];          \
                int t0 = __shfl(idt, kb | 0), t1 = __shfl(idt, kb | 1);        \
                int t2 = __shfl(idt, kb | 2), t3 = __shfl(idt, kb | 3);        \
                int t4 = __shfl(idt, kb | 4), t5 = __shfl(idt, kb | 5);        \
                int t6 = __shfl(idt, kb | 6), t7 = __shfl(idt, kb | 7);        \
                uint4 u0 = xsl[(srow + t0) * 8 + j];                           \
                uint4 u1 = xsl[(srow + t1) * 8 + j];                           \
                uint4 u2 = xsl[(srow + t2) * 8 + j];                           \
                uint4 u3 = xsl[(srow + t3) * 8 + j];                           \
                uint4 u4 = xsl[(srow + t4) * 8 + j];                           \
                uint4 u5 = xsl[(srow + t5) * 8 + j];                           \
                uint4 u6 = xsl[(srow + t6) * 8 + j];                           \
                uint4 u7 = xsl[(srow + t7) * 8 + j];                           \
                acc = pkmax4(acc,                                              \
                    pkmax4(pkmax4(pkmax4(u0, u1), pkmax4(u2, u3)),             \
                           pkmax4(pkmax4(u4, u5), pkmax4(u6, u7))));           \
            }                                                                  \
        }                                                                      \
    }

#define GEMM_TILE(tb, nb)                                                      \
    {                                                                          \
        f32x4 acc[NTW];                                                        \
        _Pragma("unroll")                                                      \
        for (int t = 0; t < NTW; ++t) acc[t] = (f32x4){0.f, 0.f, 0.f, 0.f};    \
        const int r = (nb) + mrow;                                             \
        _Pragma("unroll")                                                      \
        for (int kt = 0; kt < 4; ++kt) {                                       \
            const int q = kt * 4 + quad;                                       \
            uint4 ta = ldsb[tb][mrow][q];                                      \
            uint4 tr = xsl[((size_t)(q >> 3) * nN + r) * 8 + (q & 7)];         \
            ta.x = encdec(ta.x); ta.y = encdec(ta.y);                          \
            ta.z = encdec(ta.z); ta.w = encdec(ta.w);                          \
            tr.x = encdec(tr.x); tr.y = encdec(tr.y);                          \
            tr.z = encdec(tr.z); tr.w = encdec(tr.w);                          \
            bf16x8 aa = __builtin_bit_cast(bf16x8, ta);                        \
            bf16x8 ar = __builtin_bit_cast(bf16x8, tr);                        \
            _Pragma("unroll")                                                  \
            for (int t = 0; t < NTW; ++t) {                                    \
                const int ct = wv * NTW + t;                                   \
                bf16x8 wb0 = __builtin_bit_cast(bf16x8,                        \
                    Wf[(kt * NT + ct) * 64 + lane]);                           \
                acc[t] = __builtin_amdgcn_mfma_f32_16x16x32_bf16(              \
                    aa, wb0, acc[t], 0, 0, 0);                                 \
                bf16x8 wb1 = __builtin_bit_cast(bf16x8,                        \
                    Wf[((4 + kt) * NT + ct) * 64 + lane]);                     \
                acc[t] = __builtin_amdgcn_mfma_f32_16x16x32_bf16(              \
                    ar, wb1, acc[t], 0, 0, 0);                                 \
            }                                                                  \
        }                                                                      \
        _Pragma("unroll")                                                      \
        for (int t = 0; t < NTW; ++t) {                                        \
            const int col = (wv * NTW + t) * 16 + mrow;                        \
            const float bv = bias[col];                                        \
            _Pragma("unroll")                                                  \
            for (int rr = 0; rr < 4; ++rr) {                                   \
                const int grow = (nb) + quad * 4 + rr;                         \
                float v = acc[t][rr] + bv;                                     \
                if (RELU) v = fmaxf(v, 0.0f);                                  \
                if constexpr (ENCOUT) {                                        \
                    unsigned u = f2bf_rne(v);                                  \
                    u ^= ((u >> 15) & 1u) * 0x7FFFu;                           \
                    C[((size_t)(col >> 6) * nN + grow) * 64 + (col & 63)]      \
                        = (OutT)u;                                             \
                } else {                                                       \
                    C[(size_t)grow * BN + col] = (OutT)v;                      \
                }                                                              \
            }                                                                  \
        }                                                                      \
    }

    // ---- stage 1: gather tile0 -> lds0 ----
    {
        uint4 acc0;
        GATHER16(p0a, p0b, acc0);
        GATHER_TAIL(beg0, end0, m0, acc0);
        uint4 o;
        if (m0 > 0) { o = acc0; }
        else        { o.x = o.y = o.z = o.w = 0u; }   // enc(0)==0
        ldsb[0][nloc][s * 8 + j] = o;
    }
    __syncthreads();

    // ---- stage 2: issue tile1 gathers, then GEMM tile0 under them ----
    uint4 acc1;
    GATHER16(p1a, p1b, acc1);          // loads go in flight here
    GEMM_TILE(0, n0);                  // MFMA + root reads overlap gathers
    GATHER_TAIL(beg1, end1, m1, acc1);
    {
        uint4 o;
        if (m1 > 0) { o = acc1; }
        else        { o.x = o.y = o.z = o.w = 0u; }
        ldsb[1][nloc][s * 8 + j] = o;
    }
    __syncthreads();

    // ---- stage 3: GEMM tile1 ----
    GEMM_TILE(1, n0 + 16);

#undef GATHER16
#undef GATHER_TAIL
#undef GEMM_TILE
}

extern "C" void kernel_launch(void* const* d_in, const int* in_sizes, int n_in,
                              void* d_out, int out_size, void* d_ws, size_t ws_size,
                              hipStream_t stream) {
    const float* x   = (const float*)d_in[0];
    const int*   ei  = (const int*)d_in[1];
    const float* W1l = (const float*)d_in[2];
    const float* b1l = (const float*)d_in[3];
    const float* W1r = (const float*)d_in[4];
    const float* W2l = (const float*)d_in[5];
    const float* b2l = (const float*)d_in[6];
    const float* W2r = (const float*)d_in[7];
    float* out = (float*)d_out;

    const int* src = ei;
    const int* dst = ei + NEDGES;

    // ---- workspace layout ----
    char* ws = (char*)d_ws;
    unsigned short* xe    = (unsigned short*)ws; ws += (size_t)NNODES * 128 * 2;  // 25.6 MB sliced
    unsigned short* he    = (unsigned short*)ws; ws += (size_t)NNODES * 128 * 2;  // 25.6 MB sliced
    unsigned int* binArr    = (unsigned int*)ws; ws += (size_t)NBKT * CAP * 4;    // 7.2 MB
    unsigned int* sortedSrc = (unsigned int*)ws; ws += (size_t)NBKT * CAP * 4;    // 7.2 MB
    int* rowBeg     = (int*)ws; ws += (size_t)NNODES * 4;
    int* rowEnd     = (int*)ws; ws += (size_t)NNODES * 4;
    int* bucketFill = (int*)ws; ws += 256 * 4;
    uint4* Wf1 = (uint4*)ws; ws += 4096 * 16;   // 64 KB fragment-packed L1 weights
    uint4* Wf2 = (uint4*)ws; ws += 2048 * 16;   // 32 KB fragment-packed L2 weights

    const int gFus = NNODES / 32;               // 3125 blocks x 32 nodes (exact)

    hipMemsetAsync(bucketFill, 0, 256 * sizeof(int), stream);
    prep_kernel<<<GBIN + GCVT + GWPK, 256, 0, stream>>>(
        src, dst, binArr, bucketFill, (const float4*)x, (uint4*)xe,
        W1l, W1r, W2l, W2r, Wf1, Wf2, NEDGES);
    build_csr_kernel<<<NBKT, 512, 0, stream>>>(binArr, bucketFill, sortedSrc, rowBeg, rowEnd);

    // ---- layer 1: aggregate(xe) + GEMM -> he (sliced, encoded, relu) ----
    sage_fused2<128, true, true, unsigned short><<<gFus, 256, 0, stream>>>(
        (const uint4*)xe, rowBeg, rowEnd, sortedSrc, Wf1, b1l, he, NNODES);
    // ---- layer 2: aggregate(he) + GEMM -> out (linear f32) ----
    sage_fused2<64, false, false, float><<<gFus, 256, 0, stream>>>(
        (const uint4*)he, rowBeg, rowEnd, sortedSrc, Wf2, b2l, out, NNODES);
}